// Round 1
// baseline (10615.147 us; speedup 1.0000x reference)
//
#include <hip/hip_runtime.h>
#include <hip/hip_bf16.h>

#define BSZ 1024
#define HSZ 512
#define TSZ 48
#define INSZ 64

#define BM 64
#define BN 32
#define BK 32

__device__ __forceinline__ float fast_sigmoid(float x) {
    return 1.0f / (1.0f + __expf(-x));
}
__device__ __forceinline__ float fast_tanh(float x) {
    // tanh(x) = 2*sigmoid(2x) - 1
    return 2.0f / (1.0f + __expf(-2.0f * x)) - 1.0f;
}

// Computes gates = Ax[BSZ,Kx] @ Wx[Kx,2048] + Ah[BSZ,512] @ Wh[512,2048] + b,
// then LSTM cell update. Gate columns for hidden unit n: n, n+512, n+1024, n+1536.
// grid: (BSZ/BM, HSZ/BN), block: 256 threads.
__global__ __launch_bounds__(256) void lstm_step(
    const float* __restrict__ Ax, int ldax, int Kx,
    const float* __restrict__ Wx,
    const float* __restrict__ Ah,
    const float* __restrict__ Wh,
    const float* __restrict__ bias,
    float* __restrict__ C,
    float* __restrict__ hout)
{
    __shared__ float As[BK][BM + 4];   // transposed A tile; pad 68 (16B-aligned rows)
    __shared__ float Bs[BK][4 * BN];   // [k][gate*32 + h]

    const int tid = threadIdx.x;
    const int tx = tid & 31;   // hidden unit within BN
    const int ty = tid >> 5;   // row group (8 groups of 8 rows)
    const int m0 = blockIdx.x * BM;
    const int n0 = blockIdx.y * BN;

    float acc[8][4];
#pragma unroll
    for (int r = 0; r < 8; ++r)
#pragma unroll
        for (int g = 0; g < 4; ++g) acc[r][g] = 0.0f;

#pragma unroll 1
    for (int phase = 0; phase < 2; ++phase) {
        const float* A = phase ? Ah : Ax;
        const float* W = phase ? Wh : Wx;
        const int K   = phase ? HSZ : Kx;
        const int lda = phase ? HSZ : ldax;

#pragma unroll 1
        for (int k0 = 0; k0 < K; k0 += BK) {
            __syncthreads();
            // A tile: 64 rows x 32 k, stored transposed As[k][r]
#pragma unroll
            for (int i = 0; i < 8; ++i) {
                int idx = tid + i * 256;
                int r = idx >> 5, k = idx & 31;
                As[k][r] = A[(m0 + r) * lda + k0 + k];
            }
            // B tile: 32 k x 128 gate-cols
#pragma unroll
            for (int i = 0; i < 16; ++i) {
                int idx = tid + i * 256;
                int k = idx >> 7, c = idx & 127;
                int g = c >> 5, h = c & 31;
                Bs[k][c] = W[(k0 + k) * (4 * HSZ) + g * HSZ + n0 + h];
            }
            __syncthreads();

#pragma unroll
            for (int k = 0; k < BK; ++k) {
                float4 a0 = *reinterpret_cast<const float4*>(&As[k][ty * 8]);
                float4 a1 = *reinterpret_cast<const float4*>(&As[k][ty * 8 + 4]);
                float ar[8] = {a0.x, a0.y, a0.z, a0.w, a1.x, a1.y, a1.z, a1.w};
                float b0 = Bs[k][tx];
                float b1 = Bs[k][32 + tx];
                float b2 = Bs[k][64 + tx];
                float b3 = Bs[k][96 + tx];
#pragma unroll
                for (int r = 0; r < 8; ++r) {
                    acc[r][0] += ar[r] * b0;
                    acc[r][1] += ar[r] * b1;
                    acc[r][2] += ar[r] * b2;
                    acc[r][3] += ar[r] * b3;
                }
            }
        }
    }

    // epilogue: cell update
    const int hcol = n0 + tx;
    const float bf = bias[hcol];
    const float bi = bias[HSZ + hcol];
    const float bc = bias[2 * HSZ + hcol];
    const float bo = bias[3 * HSZ + hcol];
#pragma unroll
    for (int r = 0; r < 8; ++r) {
        int row = m0 + ty * 8 + r;
        float f = fast_sigmoid(acc[r][0] + bf);
        float i = fast_sigmoid(acc[r][1] + bi);
        float c = fast_tanh(acc[r][2] + bc);
        float o = fast_sigmoid(acc[r][3] + bo);
        float Cold = C[row * HSZ + hcol];
        float Cn = f * Cold + i * c;
        C[row * HSZ + hcol] = Cn;
        hout[row * HSZ + hcol] = o * fast_tanh(Cn);
    }
}

// out[b] = h[b,:] . w + bias ; one wave per row
__global__ __launch_bounds__(256) void fc_kernel(
    const float* __restrict__ h, const float* __restrict__ w,
    const float* __restrict__ b, float* __restrict__ out)
{
    int wave = (blockIdx.x * blockDim.x + threadIdx.x) >> 6;
    int lane = threadIdx.x & 63;
    if (wave >= BSZ) return;
    float s = 0.0f;
#pragma unroll
    for (int k = lane; k < HSZ; k += 64) s += h[wave * HSZ + k] * w[k];
#pragma unroll
    for (int off = 32; off; off >>= 1) s += __shfl_down(s, off);
    if (lane == 0) out[wave] = s + b[0];
}

extern "C" void kernel_launch(void* const* d_in, const int* in_sizes, int n_in,
                              void* d_out, int out_size, void* d_ws, size_t ws_size,
                              hipStream_t stream) {
    const float* x   = (const float*)d_in[0];
    const float* Wx0 = (const float*)d_in[1];
    const float* Wh0 = (const float*)d_in[2];
    const float* b0  = (const float*)d_in[3];
    const float* Wx1 = (const float*)d_in[4];
    const float* Wh1 = (const float*)d_in[5];
    const float* b1  = (const float*)d_in[6];
    const float* Wx2 = (const float*)d_in[7];
    const float* Wh2 = (const float*)d_in[8];
    const float* b2  = (const float*)d_in[9];
    const float* fcw = (const float*)d_in[10];
    const float* fcb = (const float*)d_in[11];

    float* ws = (float*)d_ws;
    // layout: h[2][3][B][H], C[3][B][H]
    const size_t slab = (size_t)BSZ * HSZ;
    float* hbuf = ws;
    float* Cbuf = ws + 2 * 3 * slab;
    const size_t state_bytes = (2 * 3 + 3) * slab * sizeof(float);

    hipMemsetAsync(d_ws, 0, state_bytes, stream);

    const float* WxA[3] = {Wx0, Wx1, Wx2};
    const float* WhA[3] = {Wh0, Wh1, Wh2};
    const float* bA[3]  = {b0, b1, b2};

    auto Hb = [&](int par, int l) { return hbuf + ((size_t)par * 3 + l) * slab; };
    auto Cb = [&](int l) { return Cbuf + (size_t)l * slab; };

    dim3 grid(BSZ / BM, HSZ / BN);
    dim3 block(256);

    for (int t = 0; t < TSZ; ++t) {
        int cur = t & 1, prv = cur ^ 1;
        // layer 0: x input
        lstm_step<<<grid, block, 0, stream>>>(
            x + (size_t)t * INSZ, TSZ * INSZ, INSZ, WxA[0],
            Hb(prv, 0), WhA[0], bA[0], Cb(0), Hb(cur, 0));
        // layers 1,2
        for (int l = 1; l < 3; ++l) {
            lstm_step<<<grid, block, 0, stream>>>(
                Hb(cur, l - 1), HSZ, HSZ, WxA[l],
                Hb(prv, l), WhA[l], bA[l], Cb(l), Hb(cur, l));
        }
    }
    // final FC on h[layer2] at t=47 (parity 1)
    fc_kernel<<<dim3(256), block, 0, stream>>>(Hb(1, 2), fcw, fcb, (float*)d_out);
}

// Round 4
// 3405.710 us; speedup vs baseline: 3.1169x; 3.1169x over previous
//
#include <hip/hip_runtime.h>
#include <hip/hip_bf16.h>
#include <stdint.h>

#define BSZ 1024
#define HSZ 512
#define TSZ 48
#define INSZ 64
#define GSZ 2048  // 4*HSZ

typedef __attribute__((ext_vector_type(8))) short bf16x8;
typedef __attribute__((ext_vector_type(4))) float f32x4;

#define GLDS16(g, l)                                                        \
    __builtin_amdgcn_global_load_lds(                                       \
        (const __attribute__((address_space(1))) void*)(g),                 \
        (__attribute__((address_space(3))) void*)(l), 16, 0, 0)

__device__ __forceinline__ float sigmf(float x) { return 1.0f / (1.0f + __expf(-x)); }
__device__ __forceinline__ float tanhf_(float x) { return 2.0f / (1.0f + __expf(-2.0f * x)) - 1.0f; }

// gates = [Ax | Ah] @ Wt^T + b, Wt pre-transposed+reordered [2048][Ktot] bf16 hi/lo,
// output col' = hidden*4 + gate. Fused LSTM cell epilogue.
// grid (16,16): 64 rows x 128 gate-cols per block, 256 threads (4 waves).
__global__ __launch_bounds__(256) void lstm_step_mfma(
    const __hip_bfloat16* __restrict__ Axh, const __hip_bfloat16* __restrict__ Axl,
    int ldax, int Kx,
    const __hip_bfloat16* __restrict__ Ahh, const __hip_bfloat16* __restrict__ Ahl,
    const __hip_bfloat16* __restrict__ Wth, const __hip_bfloat16* __restrict__ Wtl,
    int Ktot,
    const float* __restrict__ bias,
    float* __restrict__ C,
    __hip_bfloat16* __restrict__ hhi, __hip_bfloat16* __restrict__ hlo)
{
    __shared__ __align__(16) char lds[49152];  // Ahi 8K | Alo 8K | Bhi 16K | Blo 16K

    const int tid = threadIdx.x;
    const int lane = tid & 63;
    const int wv = tid >> 6;
    const int m0 = blockIdx.x * 64;
    const int n0 = blockIdx.y * 128;

    const int lrow = lane & 15;
    const int lk = lane >> 4;

    // swizzled ds_read offsets (read side of the XOR swizzle)
    int offA[4][2], offB[2][2];
#pragma unroll
    for (int m = 0; m < 4; ++m) {
        int row = m * 16 + lrow;
#pragma unroll
        for (int kk = 0; kk < 2; ++kk)
            offA[m][kk] = (row * 128 + (lk + kk * 4) * 16) ^ ((row & 7) << 4);
    }
#pragma unroll
    for (int j = 0; j < 2; ++j) {
        int n = wv * 32 + j * 16 + lrow;
#pragma unroll
        for (int kk = 0; kk < 2; ++kk)
            offB[j][kk] = (n * 128 + (lk + kk * 4) * 16) ^ ((n & 7) << 4);
    }

    // staging segments (source side of the XOR swizzle: pre-swizzled global k)
    int rowA[2], ksA[2];
#pragma unroll
    for (int i = 0; i < 2; ++i) {
        int seg = (wv * 2 + i) * 64 + lane;
        rowA[i] = seg >> 3;
        ksA[i] = ((seg & 7) ^ (rowA[i] & 7)) * 8;
    }
    int rowB[4], ksB[4];
#pragma unroll
    for (int i = 0; i < 4; ++i) {
        int seg = (wv * 4 + i) * 64 + lane;
        rowB[i] = seg >> 3;
        ksB[i] = ((seg & 7) ^ (rowB[i] & 7)) * 8;
    }

    char* ldsAh = lds;
    char* ldsAl = lds + 8192;
    char* ldsBh = lds + 16384;
    char* ldsBl = lds + 32768;

    f32x4 acc[4][2];
#pragma unroll
    for (int m = 0; m < 4; ++m)
#pragma unroll
        for (int j = 0; j < 2; ++j) acc[m][j] = (f32x4){0.f, 0.f, 0.f, 0.f};

    auto kstep = [&](const __hip_bfloat16* Ah_, const __hip_bfloat16* Al_, int ldA,
                     int kA, int kW) {
        __syncthreads();  // previous compute done before overwriting LDS
#pragma unroll
        for (int i = 0; i < 2; ++i) {
            size_t ro = (size_t)(m0 + rowA[i]) * ldA + kA + ksA[i];
            GLDS16(Ah_ + ro, ldsAh + (wv * 2 + i) * 1024);
            GLDS16(Al_ + ro, ldsAl + (wv * 2 + i) * 1024);
        }
#pragma unroll
        for (int i = 0; i < 4; ++i) {
            size_t ro = (size_t)(n0 + rowB[i]) * Ktot + kW + ksB[i];
            GLDS16(Wth + ro, ldsBh + (wv * 4 + i) * 1024);
            GLDS16(Wtl + ro, ldsBl + (wv * 4 + i) * 1024);
        }
        __syncthreads();  // compiler drains vmcnt before barrier
#pragma unroll
        for (int kk = 0; kk < 2; ++kk) {
            bf16x8 a_h[4], a_l[4], b_h[2], b_l[2];
#pragma unroll
            for (int m = 0; m < 4; ++m) {
                a_h[m] = *(const bf16x8*)(ldsAh + offA[m][kk]);
                a_l[m] = *(const bf16x8*)(ldsAl + offA[m][kk]);
            }
#pragma unroll
            for (int j = 0; j < 2; ++j) {
                b_h[j] = *(const bf16x8*)(ldsBh + offB[j][kk]);
                b_l[j] = *(const bf16x8*)(ldsBl + offB[j][kk]);
            }
#pragma unroll
            for (int m = 0; m < 4; ++m)
#pragma unroll
                for (int j = 0; j < 2; ++j) {
                    acc[m][j] = __builtin_amdgcn_mfma_f32_16x16x32_bf16(a_h[m], b_h[j], acc[m][j], 0, 0, 0);
                    acc[m][j] = __builtin_amdgcn_mfma_f32_16x16x32_bf16(a_l[m], b_h[j], acc[m][j], 0, 0, 0);
                    acc[m][j] = __builtin_amdgcn_mfma_f32_16x16x32_bf16(a_h[m], b_l[j], acc[m][j], 0, 0, 0);
                }
        }
    };

#pragma unroll 1
    for (int k0 = 0; k0 < Kx; k0 += 64) kstep(Axh, Axl, ldax, k0, k0);
#pragma unroll 1
    for (int k0 = 0; k0 < HSZ; k0 += 64) kstep(Ahh, Ahl, HSZ, k0, Kx + k0);

    // ---- epilogue: acc -> LDS [64][132] f32, then fused cell update ----
    __syncthreads();
    float* gt = (float*)lds;
#pragma unroll
    for (int m = 0; m < 4; ++m)
#pragma unroll
        for (int j = 0; j < 2; ++j) {
            int col = wv * 32 + j * 16 + lrow;
            int rb = m * 16 + lk * 4;
#pragma unroll
            for (int r = 0; r < 4; ++r) gt[(rb + r) * 132 + col] = acc[m][j][r];
        }
    __syncthreads();

    const int n_l = tid & 31;
    const int rb2 = (tid >> 5) * 8;
    const int n_g = (n0 >> 2) + n_l;  // global hidden unit
    const float bf = bias[n_g], bi = bias[HSZ + n_g];
    const float bc = bias[2 * HSZ + n_g], bo = bias[3 * HSZ + n_g];
#pragma unroll
    for (int r = 0; r < 8; ++r) {
        int row = rb2 + r;
        int rg = m0 + row;
        float4 g4 = *(const float4*)&gt[row * 132 + n_l * 4];  // f,i,c,o
        float f = sigmf(g4.x + bf);
        float i_ = sigmf(g4.y + bi);
        float c_ = tanhf_(g4.z + bc);
        float o_ = sigmf(g4.w + bo);
        size_t idx = (size_t)rg * HSZ + n_g;
        float Cn = f * C[idx] + i_ * c_;
        C[idx] = Cn;
        float hv = o_ * tanhf_(Cn);
        __hip_bfloat16 hh = __float2bfloat16(hv);
        hhi[idx] = hh;
        hlo[idx] = __float2bfloat16(hv - __bfloat162float(hh));
    }
}

// x[B][T][64] f32 -> xt[T][B][64] bf16 hi/lo
__global__ __launch_bounds__(256) void convert_x(const float* __restrict__ x,
                                                 __hip_bfloat16* __restrict__ xh,
                                                 __hip_bfloat16* __restrict__ xl)
{
    int idx = blockIdx.x * 256 + threadIdx.x;  // B*T*16
    int i4 = idx & 15;
    int bt = idx >> 4;
    int t = bt % TSZ;
    int b = bt / TSZ;
    float4 v = *(const float4*)(x + ((size_t)b * TSZ + t) * INSZ + i4 * 4);
    size_t o = ((size_t)t * BSZ + b) * INSZ + i4 * 4;
    float vv[4] = {v.x, v.y, v.z, v.w};
#pragma unroll
    for (int j = 0; j < 4; ++j) {
        __hip_bfloat16 h = __float2bfloat16(vv[j]);
        xh[o + j] = h;
        xl[o + j] = __float2bfloat16(vv[j] - __bfloat162float(h));
    }
}

// W[k][gate*512+n] f32 (Wx then Wh stacked in k) -> Wt[n*4+gate][k] bf16 hi/lo
__global__ __launch_bounds__(256) void convert_w(
    const float* __restrict__ Wx, const float* __restrict__ Wh, int Kx, int Ktot,
    __hip_bfloat16* __restrict__ outh, __hip_bfloat16* __restrict__ outl)
{
    __shared__ float tile[64][65];
    int k0 = blockIdx.x * 64;
    int c0 = blockIdx.y * 64;
    int nb = c0 >> 2;
    const float* src;
    int krel;
    if (k0 < Kx) { src = Wx; krel = k0; } else { src = Wh; krel = k0 - Kx; }
#pragma unroll
    for (int i = 0; i < 16; ++i) {
        int idx = threadIdx.x + i * 256;
        int k_l = idx >> 6, c_l = idx & 63;
        int g = c_l >> 4, n_l = c_l & 15;
        tile[k_l][n_l * 4 + g] = src[(size_t)(krel + k_l) * GSZ + g * HSZ + nb + n_l];
    }
    __syncthreads();
#pragma unroll
    for (int i = 0; i < 16; ++i) {
        int idx = threadIdx.x + i * 256;
        int r_l = idx >> 6, k_l = idx & 63;
        float v = tile[k_l][r_l];
        __hip_bfloat16 h = __float2bfloat16(v);
        size_t o = (size_t)(c0 + r_l) * Ktot + k0 + k_l;
        outh[o] = h;
        outl[o] = __float2bfloat16(v - __bfloat162float(h));
    }
}

__global__ __launch_bounds__(256) void fc_kernel(
    const __hip_bfloat16* __restrict__ hh, const __hip_bfloat16* __restrict__ hl,
    const float* __restrict__ w, const float* __restrict__ b, float* __restrict__ out)
{
    int wave = (blockIdx.x * 256 + threadIdx.x) >> 6;
    int lane = threadIdx.x & 63;
    if (wave >= BSZ) return;
    float s = 0.0f;
#pragma unroll
    for (int k = lane; k < HSZ; k += 64)
        s += (__bfloat162float(hh[wave * HSZ + k]) + __bfloat162float(hl[wave * HSZ + k])) * w[k];
#pragma unroll
    for (int off = 32; off; off >>= 1) s += __shfl_down(s, off);
    if (lane == 0) out[wave] = s + b[0];
}

extern "C" void kernel_launch(void* const* d_in, const int* in_sizes, int n_in,
                              void* d_out, int out_size, void* d_ws, size_t ws_size,
                              hipStream_t stream) {
    const float* x   = (const float*)d_in[0];
    const float* Wx0 = (const float*)d_in[1];
    const float* Wh0 = (const float*)d_in[2];
    const float* b0  = (const float*)d_in[3];
    const float* Wx1 = (const float*)d_in[4];
    const float* Wh1 = (const float*)d_in[5];
    const float* b1  = (const float*)d_in[6];
    const float* Wx2 = (const float*)d_in[7];
    const float* Wh2 = (const float*)d_in[8];
    const float* b2  = (const float*)d_in[9];
    const float* fcw = (const float*)d_in[10];
    const float* fcb = (const float*)d_in[11];

    char* p = (char*)d_ws;
    const size_t hslab = (size_t)BSZ * HSZ * sizeof(__hip_bfloat16);  // 1 MiB
    __hip_bfloat16* hbuf = (__hip_bfloat16*)p;  // [par][layer][hi/lo] 12 slabs
    p += 12 * hslab;
    float* Cbuf = (float*)p;  // [3][B][H] f32
    p += 3 * (size_t)BSZ * HSZ * sizeof(float);
    const size_t zero_bytes = (size_t)(p - (char*)d_ws);

    const size_t xslab = (size_t)TSZ * BSZ * INSZ * sizeof(__hip_bfloat16);
    __hip_bfloat16* xth = (__hip_bfloat16*)p; p += xslab;
    __hip_bfloat16* xtl = (__hip_bfloat16*)p; p += xslab;

    const int K0 = INSZ + HSZ;   // 576
    const int K12 = 2 * HSZ;     // 1024
    const size_t w0s = (size_t)GSZ * K0 * sizeof(__hip_bfloat16);
    const size_t w12s = (size_t)GSZ * K12 * sizeof(__hip_bfloat16);
    __hip_bfloat16* w0h = (__hip_bfloat16*)p; p += w0s;
    __hip_bfloat16* w0l = (__hip_bfloat16*)p; p += w0s;
    __hip_bfloat16* w1h = (__hip_bfloat16*)p; p += w12s;
    __hip_bfloat16* w1l = (__hip_bfloat16*)p; p += w12s;
    __hip_bfloat16* w2h = (__hip_bfloat16*)p; p += w12s;
    __hip_bfloat16* w2l = (__hip_bfloat16*)p; p += w12s;

    hipMemsetAsync(d_ws, 0, zero_bytes, stream);

    convert_x<<<dim3(BSZ * TSZ * 16 / 256), dim3(256), 0, stream>>>(x, xth, xtl);
    convert_w<<<dim3(K0 / 64, GSZ / 64), dim3(256), 0, stream>>>(Wx0, Wh0, INSZ, K0, w0h, w0l);
    convert_w<<<dim3(K12 / 64, GSZ / 64), dim3(256), 0, stream>>>(Wx1, Wh1, HSZ, K12, w1h, w1l);
    convert_w<<<dim3(K12 / 64, GSZ / 64), dim3(256), 0, stream>>>(Wx2, Wh2, HSZ, K12, w2h, w2l);

    auto Hb = [&](int par, int l, int hilo) {
        return hbuf + ((size_t)(par * 3 + l) * 2 + hilo) * BSZ * HSZ;
    };
    auto Cb = [&](int l) { return Cbuf + (size_t)l * BSZ * HSZ; };

    const __hip_bfloat16* WH[3] = {w0h, w1h, w2h};
    const __hip_bfloat16* WL[3] = {w0l, w1l, w2l};
    const float* BI[3] = {b0, b1, b2};
    const int KT[3] = {K0, K12, K12};
    const int KX[3] = {INSZ, HSZ, HSZ};

    dim3 grid(BSZ / 64, GSZ / 128);
    dim3 block(256);

    for (int t = 0; t < TSZ; ++t) {
        int cur = t & 1, prv = cur ^ 1;
        // layer 0: x input
        lstm_step_mfma<<<grid, block, 0, stream>>>(
            xth + (size_t)t * BSZ * INSZ, xtl + (size_t)t * BSZ * INSZ, INSZ, KX[0],
            Hb(prv, 0, 0), Hb(prv, 0, 1), WH[0], WL[0], KT[0], BI[0],
            Cb(0), Hb(cur, 0, 0), Hb(cur, 0, 1));
        for (int l = 1; l < 3; ++l) {
            lstm_step_mfma<<<grid, block, 0, stream>>>(
                Hb(cur, l - 1, 0), Hb(cur, l - 1, 1), HSZ, KX[l],
                Hb(prv, l, 0), Hb(prv, l, 1), WH[l], WL[l], KT[l], BI[l],
                Cb(l), Hb(cur, l, 0), Hb(cur, l, 1));
        }
    }
    fc_kernel<<<dim3(BSZ / 4), block, 0, stream>>>(Hb(1, 2, 0), Hb(1, 2, 1), fcw, fcb, (float*)d_out);
}

// Round 5
// 1868.858 us; speedup vs baseline: 5.6800x; 1.8223x over previous
//
#include <hip/hip_runtime.h>
#include <hip/hip_bf16.h>
#include <stdint.h>

#define BSZ 1024
#define HSZ 512
#define TSZ 48
#define INSZ 64
#define GSZ 2048  // 4*HSZ

typedef __attribute__((ext_vector_type(8))) short bf16x8;
typedef __attribute__((ext_vector_type(4))) float f32x4;

#define GLDS16(g, l)                                                        \
    __builtin_amdgcn_global_load_lds(                                       \
        (const __attribute__((address_space(1))) void*)(g),                 \
        (__attribute__((address_space(3))) void*)(l), 16, 0, 0)

__device__ __forceinline__ float sigmf(float x) { return 1.0f / (1.0f + __expf(-x)); }
__device__ __forceinline__ float tanhf_(float x) { return 2.0f / (1.0f + __expf(-2.0f * x)) - 1.0f; }

// One diagonal d = t + l of the (t,l) grid. blockIdx.z selects the cell:
// l = lmin + z, t = d - l. All cells in a diagonal are independent
// (deps (t,l-1) and (t-1,l) are both in diagonal d-1).
// Per cell: gates = [Ax | Ah] @ Wt^T + b -> fused LSTM cell update.
// Wt pre-transposed+reordered [2048][Ktot] bf16 hi/lo, col' = hidden*4 + gate.
// grid (16,16,ncells): 64 rows x 128 gate-cols per block, 256 threads.
__global__ __launch_bounds__(256, 3) void lstm_diag(
    const __hip_bfloat16* __restrict__ xth, const __hip_bfloat16* __restrict__ xtl,
    __hip_bfloat16* __restrict__ hbuf,   // [par][layer][hilo][B*H]
    float* __restrict__ Cbuf,            // [layer][B*H]
    const __hip_bfloat16* __restrict__ W0h, const __hip_bfloat16* __restrict__ W0l,
    const __hip_bfloat16* __restrict__ W1h, const __hip_bfloat16* __restrict__ W1l,
    const __hip_bfloat16* __restrict__ W2h, const __hip_bfloat16* __restrict__ W2l,
    const float* __restrict__ b0, const float* __restrict__ b1,
    const float* __restrict__ b2,
    int d, int lmin)
{
    __shared__ __align__(16) char lds[49152];  // Ahi 8K | Alo 8K | Bhi 16K | Blo 16K

    const int l = lmin + blockIdx.z;
    const int t = d - l;
    const size_t slab = (size_t)BSZ * HSZ;
    __hip_bfloat16* hb = hbuf;
    auto Hb = [&](int par, int ll, int hilo) {
        return hb + (((size_t)par * 3 + ll) * 2 + hilo) * slab;
    };

    const __hip_bfloat16* Wth = (l == 0) ? W0h : (l == 1) ? W1h : W2h;
    const __hip_bfloat16* Wtl = (l == 0) ? W0l : (l == 1) ? W1l : W2l;
    const float* bias = (l == 0) ? b0 : (l == 1) ? b1 : b2;
    const int Kx   = (l == 0) ? INSZ : HSZ;
    const int Ktot = Kx + HSZ;
    const int cur = t & 1, prv = cur ^ 1;
    const __hip_bfloat16* Axh = (l == 0) ? xth + (size_t)t * BSZ * INSZ : Hb(cur, l - 1, 0);
    const __hip_bfloat16* Axl = (l == 0) ? xtl + (size_t)t * BSZ * INSZ : Hb(cur, l - 1, 1);
    const int ldax = Kx;
    const __hip_bfloat16* Ahh = Hb(prv, l, 0);
    const __hip_bfloat16* Ahl = Hb(prv, l, 1);
    float* C = Cbuf + (size_t)l * slab;
    __hip_bfloat16* hhi = Hb(cur, l, 0);
    __hip_bfloat16* hlo = Hb(cur, l, 1);

    // XCD-aware bijective swizzle within the 256-block z-slice (256 % 8 == 0):
    // each XCD gets 32 consecutive logical tiles -> 2 weight panels in its L2.
    const int bid = blockIdx.x + (blockIdx.y << 4);
    const int swz = (bid & 7) * 32 + (bid >> 3);
    const int m0 = (swz & 15) * 64;
    const int n0 = (swz >> 4) * 128;

    const int tid = threadIdx.x;
    const int lane = tid & 63;
    const int wv = tid >> 6;
    const int lrow = lane & 15;
    const int lk = lane >> 4;

    // swizzled ds_read offsets (read side of the XOR swizzle)
    int offA[4][2], offB[2][2];
#pragma unroll
    for (int m = 0; m < 4; ++m) {
        int row = m * 16 + lrow;
#pragma unroll
        for (int kk = 0; kk < 2; ++kk)
            offA[m][kk] = (row * 128 + (lk + kk * 4) * 16) ^ ((row & 7) << 4);
    }
#pragma unroll
    for (int j = 0; j < 2; ++j) {
        int n = wv * 32 + j * 16 + lrow;
#pragma unroll
        for (int kk = 0; kk < 2; ++kk)
            offB[j][kk] = (n * 128 + (lk + kk * 4) * 16) ^ ((n & 7) << 4);
    }

    // staging segments (source side of the XOR swizzle: pre-swizzled global k)
    int rowA[2], ksA[2];
#pragma unroll
    for (int i = 0; i < 2; ++i) {
        int seg = (wv * 2 + i) * 64 + lane;
        rowA[i] = seg >> 3;
        ksA[i] = ((seg & 7) ^ (rowA[i] & 7)) * 8;
    }
    int rowB[4], ksB[4];
#pragma unroll
    for (int i = 0; i < 4; ++i) {
        int seg = (wv * 4 + i) * 64 + lane;
        rowB[i] = seg >> 3;
        ksB[i] = ((seg & 7) ^ (rowB[i] & 7)) * 8;
    }

    char* ldsAh = lds;
    char* ldsAl = lds + 8192;
    char* ldsBh = lds + 16384;
    char* ldsBl = lds + 32768;

    f32x4 acc[4][2];
#pragma unroll
    for (int m = 0; m < 4; ++m)
#pragma unroll
        for (int j = 0; j < 2; ++j) acc[m][j] = (f32x4){0.f, 0.f, 0.f, 0.f};

    auto kstep = [&](const __hip_bfloat16* Ah_, const __hip_bfloat16* Al_, int ldA,
                     int kA, int kW) {
        __syncthreads();  // previous compute done before overwriting LDS
#pragma unroll
        for (int i = 0; i < 2; ++i) {
            size_t ro = (size_t)(m0 + rowA[i]) * ldA + kA + ksA[i];
            GLDS16(Ah_ + ro, ldsAh + (wv * 2 + i) * 1024);
            GLDS16(Al_ + ro, ldsAl + (wv * 2 + i) * 1024);
        }
#pragma unroll
        for (int i = 0; i < 4; ++i) {
            size_t ro = (size_t)(n0 + rowB[i]) * Ktot + kW + ksB[i];
            GLDS16(Wth + ro, ldsBh + (wv * 4 + i) * 1024);
            GLDS16(Wtl + ro, ldsBl + (wv * 4 + i) * 1024);
        }
        __syncthreads();  // compiler drains vmcnt before barrier
#pragma unroll
        for (int kk = 0; kk < 2; ++kk) {
            bf16x8 a_h[4], a_l[4], b_h[2], b_l[2];
#pragma unroll
            for (int m = 0; m < 4; ++m) {
                a_h[m] = *(const bf16x8*)(ldsAh + offA[m][kk]);
                a_l[m] = *(const bf16x8*)(ldsAl + offA[m][kk]);
            }
#pragma unroll
            for (int j = 0; j < 2; ++j) {
                b_h[j] = *(const bf16x8*)(ldsBh + offB[j][kk]);
                b_l[j] = *(const bf16x8*)(ldsBl + offB[j][kk]);
            }
#pragma unroll
            for (int m = 0; m < 4; ++m)
#pragma unroll
                for (int j = 0; j < 2; ++j) {
                    acc[m][j] = __builtin_amdgcn_mfma_f32_16x16x32_bf16(a_h[m], b_h[j], acc[m][j], 0, 0, 0);
                    acc[m][j] = __builtin_amdgcn_mfma_f32_16x16x32_bf16(a_l[m], b_h[j], acc[m][j], 0, 0, 0);
                    acc[m][j] = __builtin_amdgcn_mfma_f32_16x16x32_bf16(a_h[m], b_l[j], acc[m][j], 0, 0, 0);
                }
        }
    };

#pragma unroll 1
    for (int k0 = 0; k0 < Kx; k0 += 64) kstep(Axh, Axl, ldax, k0, k0);
#pragma unroll 1
    for (int k0 = 0; k0 < HSZ; k0 += 64) kstep(Ahh, Ahl, HSZ, k0, Kx + k0);

    // ---- epilogue: acc -> LDS [64][132] f32, then fused cell update ----
    __syncthreads();
    float* gt = (float*)lds;
#pragma unroll
    for (int m = 0; m < 4; ++m)
#pragma unroll
        for (int j = 0; j < 2; ++j) {
            int col = wv * 32 + j * 16 + lrow;
            int rb = m * 16 + lk * 4;
#pragma unroll
            for (int r = 0; r < 4; ++r) gt[(rb + r) * 132 + col] = acc[m][j][r];
        }
    __syncthreads();

    const int n_l = tid & 31;
    const int rb2 = (tid >> 5) * 8;
    const int n_g = (n0 >> 2) + n_l;  // global hidden unit
    const float bf = bias[n_g], bi = bias[HSZ + n_g];
    const float bc = bias[2 * HSZ + n_g], bo = bias[3 * HSZ + n_g];
#pragma unroll
    for (int r = 0; r < 8; ++r) {
        int row = rb2 + r;
        int rg = m0 + row;
        float4 g4 = *(const float4*)&gt[row * 132 + n_l * 4];  // f,i,c,o
        float f = sigmf(g4.x + bf);
        float i_ = sigmf(g4.y + bi);
        float c_ = tanhf_(g4.z + bc);
        float o_ = sigmf(g4.w + bo);
        size_t idx = (size_t)rg * HSZ + n_g;
        float Cn = f * C[idx] + i_ * c_;
        C[idx] = Cn;
        float hv = o_ * tanhf_(Cn);
        __hip_bfloat16 hh = __float2bfloat16(hv);
        hhi[idx] = hh;
        hlo[idx] = __float2bfloat16(hv - __bfloat162float(hh));
    }
}

// x[B][T][64] f32 -> xt[T][B][64] bf16 hi/lo
__global__ __launch_bounds__(256) void convert_x(const float* __restrict__ x,
                                                 __hip_bfloat16* __restrict__ xh,
                                                 __hip_bfloat16* __restrict__ xl)
{
    int idx = blockIdx.x * 256 + threadIdx.x;  // B*T*16
    int i4 = idx & 15;
    int bt = idx >> 4;
    int t = bt % TSZ;
    int b = bt / TSZ;
    float4 v = *(const float4*)(x + ((size_t)b * TSZ + t) * INSZ + i4 * 4);
    size_t o = ((size_t)t * BSZ + b) * INSZ + i4 * 4;
    float vv[4] = {v.x, v.y, v.z, v.w};
#pragma unroll
    for (int j = 0; j < 4; ++j) {
        __hip_bfloat16 h = __float2bfloat16(vv[j]);
        xh[o + j] = h;
        xl[o + j] = __float2bfloat16(vv[j] - __bfloat162float(h));
    }
}

// W[k][gate*512+n] f32 (Wx then Wh stacked in k) -> Wt[n*4+gate][k] bf16 hi/lo
__global__ __launch_bounds__(256) void convert_w(
    const float* __restrict__ Wx, const float* __restrict__ Wh, int Kx, int Ktot,
    __hip_bfloat16* __restrict__ outh, __hip_bfloat16* __restrict__ outl)
{
    __shared__ float tile[64][65];
    int k0 = blockIdx.x * 64;
    int c0 = blockIdx.y * 64;
    int nb = c0 >> 2;
    const float* src;
    int krel;
    if (k0 < Kx) { src = Wx; krel = k0; } else { src = Wh; krel = k0 - Kx; }
#pragma unroll
    for (int i = 0; i < 16; ++i) {
        int idx = threadIdx.x + i * 256;
        int k_l = idx >> 6, c_l = idx & 63;
        int g = c_l >> 4, n_l = c_l & 15;
        tile[k_l][n_l * 4 + g] = src[(size_t)(krel + k_l) * GSZ + g * HSZ + nb + n_l];
    }
    __syncthreads();
#pragma unroll
    for (int i = 0; i < 16; ++i) {
        int idx = threadIdx.x + i * 256;
        int r_l = idx >> 6, k_l = idx & 63;
        float v = tile[k_l][r_l];
        __hip_bfloat16 h = __float2bfloat16(v);
        size_t o = (size_t)(c0 + r_l) * Ktot + k0 + k_l;
        outh[o] = h;
        outl[o] = __float2bfloat16(v - __bfloat162float(h));
    }
}

__global__ __launch_bounds__(256) void fc_kernel(
    const __hip_bfloat16* __restrict__ hh, const __hip_bfloat16* __restrict__ hl,
    const float* __restrict__ w, const float* __restrict__ b, float* __restrict__ out)
{
    int wave = (blockIdx.x * 256 + threadIdx.x) >> 6;
    int lane = threadIdx.x & 63;
    if (wave >= BSZ) return;
    float s = 0.0f;
#pragma unroll
    for (int k = lane; k < HSZ; k += 64)
        s += (__bfloat162float(hh[wave * HSZ + k]) + __bfloat162float(hl[wave * HSZ + k])) * w[k];
#pragma unroll
    for (int off = 32; off; off >>= 1) s += __shfl_down(s, off);
    if (lane == 0) out[wave] = s + b[0];
}

extern "C" void kernel_launch(void* const* d_in, const int* in_sizes, int n_in,
                              void* d_out, int out_size, void* d_ws, size_t ws_size,
                              hipStream_t stream) {
    const float* x   = (const float*)d_in[0];
    const float* Wx0 = (const float*)d_in[1];
    const float* Wh0 = (const float*)d_in[2];
    const float* b0  = (const float*)d_in[3];
    const float* Wx1 = (const float*)d_in[4];
    const float* Wh1 = (const float*)d_in[5];
    const float* b1  = (const float*)d_in[6];
    const float* Wx2 = (const float*)d_in[7];
    const float* Wh2 = (const float*)d_in[8];
    const float* b2  = (const float*)d_in[9];
    const float* fcw = (const float*)d_in[10];
    const float* fcb = (const float*)d_in[11];

    char* p = (char*)d_ws;
    const size_t hslab = (size_t)BSZ * HSZ * sizeof(__hip_bfloat16);  // 1 MiB
    __hip_bfloat16* hbuf = (__hip_bfloat16*)p;  // [par][layer][hi/lo] 12 slabs
    p += 12 * hslab;
    float* Cbuf = (float*)p;  // [3][B][H] f32
    p += 3 * (size_t)BSZ * HSZ * sizeof(float);
    const size_t zero_bytes = (size_t)(p - (char*)d_ws);

    const size_t xslab = (size_t)TSZ * BSZ * INSZ * sizeof(__hip_bfloat16);
    __hip_bfloat16* xth = (__hip_bfloat16*)p; p += xslab;
    __hip_bfloat16* xtl = (__hip_bfloat16*)p; p += xslab;

    const int K0 = INSZ + HSZ;   // 576
    const int K12 = 2 * HSZ;     // 1024
    const size_t w0s = (size_t)GSZ * K0 * sizeof(__hip_bfloat16);
    const size_t w12s = (size_t)GSZ * K12 * sizeof(__hip_bfloat16);
    __hip_bfloat16* w0h = (__hip_bfloat16*)p; p += w0s;
    __hip_bfloat16* w0l = (__hip_bfloat16*)p; p += w0s;
    __hip_bfloat16* w1h = (__hip_bfloat16*)p; p += w12s;
    __hip_bfloat16* w1l = (__hip_bfloat16*)p; p += w12s;
    __hip_bfloat16* w2h = (__hip_bfloat16*)p; p += w12s;
    __hip_bfloat16* w2l = (__hip_bfloat16*)p; p += w12s;

    hipMemsetAsync(d_ws, 0, zero_bytes, stream);

    convert_x<<<dim3(BSZ * TSZ * 16 / 256), dim3(256), 0, stream>>>(x, xth, xtl);
    convert_w<<<dim3(K0 / 64, GSZ / 64), dim3(256), 0, stream>>>(Wx0, Wh0, INSZ, K0, w0h, w0l);
    convert_w<<<dim3(K12 / 64, GSZ / 64), dim3(256), 0, stream>>>(Wx1, Wh1, HSZ, K12, w1h, w1l);
    convert_w<<<dim3(K12 / 64, GSZ / 64), dim3(256), 0, stream>>>(Wx2, Wh2, HSZ, K12, w2h, w2l);

    // diagonal wavefront: d = t + l, cells (t,l) with t+l == d are independent
    for (int dgn = 0; dgn < TSZ + 2; ++dgn) {
        int lmin = (dgn - (TSZ - 1)) > 0 ? (dgn - (TSZ - 1)) : 0;
        int lmax = dgn < 2 ? dgn : 2;
        int ncells = lmax - lmin + 1;
        lstm_diag<<<dim3(16, 16, ncells), dim3(256), 0, stream>>>(
            xth, xtl, hbuf, Cbuf,
            w0h, w0l, w1h, w1l, w2h, w2l,
            b0, b1, b2, dgn, lmin);
    }

    // h of layer 2 at t=47 lives at parity 47&1 = 1
    __hip_bfloat16* h2h = hbuf + (((size_t)1 * 3 + 2) * 2 + 0) * BSZ * HSZ;
    __hip_bfloat16* h2l = hbuf + (((size_t)1 * 3 + 2) * 2 + 1) * BSZ * HSZ;
    fc_kernel<<<dim3(BSZ / 4), dim3(256), 0, stream>>>(h2h, h2l, fcw, fcb, (float*)d_out);
}